// Round 3
// baseline (14435.394 us; speedup 1.0000x reference)
//
#include <hip/hip_runtime.h>
#include <cstdint>
#include <cstddef>

// ---------------------------------------------------------------------------
// HeteroRelConv: 3 layers x 7 SAGE relations, H=64, fp32.
// Aggregate-first, dst-chunked:
//   per relation r (src S, dst D):  for each dst chunk [c0,c1):
//     agg[d-c0] += x_S[src]          (atomics, 51MB chunk, L2/L3-hot)
//     new_D[c0:c1] += (agg/cnt) @ Wl_r.T      (fused rowdiv in GEMM)
//   per type D: new_D starts as x_D @ (WrA+WrB).T + bias; ReLU fused into the
//   last relation's chunk-GEMM. Update order a,b,t,m keeps sources pre-layer.
// Peak workspace ~806 MB, guarded against ws_size.
// ---------------------------------------------------------------------------

static inline int ceildiv_i(long a, long b){ return (int)((a + b - 1) / b); }

__global__ __launch_bounds__(256)
void count_kernel(const int* __restrict__ dst, int n_e, int* __restrict__ cnt)
{
    int i = blockIdx.x * 256 + threadIdx.x;
    if (i < n_e) atomicAdd(&cnt[dst[i]], 1);
}

__global__ __launch_bounds__(256)
void i2f_kernel(int* __restrict__ buf, int n)
{
    int i = blockIdx.x * 256 + threadIdx.x;
    if (i < n) {
        int c = buf[i];
        ((float*)buf)[i] = (float)c;   // in-place int count -> float count
    }
}

// aggregate-first chunked scatter: one wave per edge, lane = feature
__global__ __launch_bounds__(256)
void scatter_chunk_kernel(const float* __restrict__ x, const int* __restrict__ srcv,
                          const int* __restrict__ dstv, int c0, int c1,
                          float* __restrict__ agg, int n_e)
{
    long idx = (long)blockIdx.x * 256 + threadIdx.x;
    int e = (int)(idx >> 6);
    if (e >= n_e) return;
    int d = dstv[e];                   // wave-uniform
    if (d < c0 || d >= c1) return;     // wave-uniform branch
    int c = (int)(idx & 63);
    int s = srcv[e];
    atomicAdd(agg + (long)(d - c0) * 64 + c, x[(long)s * 64 + c]);
}

// Y[nrows,64] = act( (X * 1/max(rowdiv,1)) @ (W1 (+W2)).T + Cin + b1 (+b2) )
// act: 0 none, 1 relu, 2 softplus
__global__ __launch_bounds__(256)
void gemm64_kernel(const float* __restrict__ X, int nrows,
                   const float* __restrict__ W1, const float* __restrict__ W2,
                   const float* __restrict__ Cin,
                   const float* __restrict__ b1, const float* __restrict__ b2,
                   const float* __restrict__ rowdiv,
                   float* __restrict__ Y, int act)
{
    __shared__ __align__(16) float wl[64 * 64];    // wl[k*64 + j] = W[j][k]
    __shared__ __align__(16) float xl[64 * 132];   // xl[k*132 + row], rows 0..127

    int tid = threadIdx.x;

    // ---- stage W transposed ----
    {
        int j  = tid & 63;
        int kq = (tid >> 6) * 16;
        #pragma unroll
        for (int i = 0; i < 4; ++i) {
            int k = kq + i * 4;
            float4 w = *(const float4*)(W1 + j * 64 + k);
            if (W2) {
                float4 w2 = *(const float4*)(W2 + j * 64 + k);
                w.x += w2.x; w.y += w2.y; w.z += w2.z; w.w += w2.w;
            }
            wl[(k + 0) * 64 + j] = w.x;
            wl[(k + 1) * 64 + j] = w.y;
            wl[(k + 2) * 64 + j] = w.z;
            wl[(k + 3) * 64 + j] = w.w;
        }
    }

    long row0 = (long)blockIdx.x * 128;

    // ---- stage X transposed (coalesced float4 reads) ----
    {
        #pragma unroll
        for (int i = 0; i < 8; ++i) {
            long f   = (long)(tid + i * 256) * 4;
            int lrow = (int)(f >> 6);
            int k0   = (int)(f & 63);
            long grow = row0 + lrow;
            float4 x = make_float4(0.f, 0.f, 0.f, 0.f);
            if (grow < nrows) {
                x = *(const float4*)(X + grow * 64 + k0);
                if (rowdiv) {
                    float rs = 1.0f / fmaxf(rowdiv[grow], 1.0f);
                    x.x *= rs; x.y *= rs; x.z *= rs; x.w *= rs;
                }
            }
            xl[(k0 + 0) * 132 + lrow] = x.x;
            xl[(k0 + 1) * 132 + lrow] = x.y;
            xl[(k0 + 2) * 132 + lrow] = x.z;
            xl[(k0 + 3) * 132 + lrow] = x.w;
        }
    }
    __syncthreads();

    int tm = tid & 31;
    int tn = tid >> 5;

    float acc[4][8];
    #pragma unroll
    for (int r = 0; r < 4; ++r)
        #pragma unroll
        for (int c = 0; c < 8; ++c) acc[r][c] = 0.f;

    #pragma unroll 8
    for (int k = 0; k < 64; ++k) {
        float4 xv = *(const float4*)(xl + k * 132 + tm * 4);
        float4 w0 = *(const float4*)(wl + k * 64 + tn * 8);
        float4 w1 = *(const float4*)(wl + k * 64 + tn * 8 + 4);
        float xr[4] = { xv.x, xv.y, xv.z, xv.w };
        float wc[8] = { w0.x, w0.y, w0.z, w0.w, w1.x, w1.y, w1.z, w1.w };
        #pragma unroll
        for (int r = 0; r < 4; ++r)
            #pragma unroll
            for (int c = 0; c < 8; ++c)
                acc[r][c] = fmaf(xr[r], wc[c], acc[r][c]);
    }

    #pragma unroll
    for (int r = 0; r < 4; ++r) {
        long grow = row0 + tm * 4 + r;
        if (grow < nrows) {
            int col0 = tn * 8;
            float v[8];
            #pragma unroll
            for (int c = 0; c < 8; ++c) v[c] = acc[r][c];
            if (Cin) {
                float4 c0v = *(const float4*)(Cin + grow * 64 + col0);
                float4 c1v = *(const float4*)(Cin + grow * 64 + col0 + 4);
                v[0] += c0v.x; v[1] += c0v.y; v[2] += c0v.z; v[3] += c0v.w;
                v[4] += c1v.x; v[5] += c1v.y; v[6] += c1v.z; v[7] += c1v.w;
            }
            if (b1) {
                #pragma unroll
                for (int c = 0; c < 8; ++c) v[c] += b1[col0 + c];
            }
            if (b2) {
                #pragma unroll
                for (int c = 0; c < 8; ++c) v[c] += b2[col0 + c];
            }
            if (act == 1) {
                #pragma unroll
                for (int c = 0; c < 8; ++c) v[c] = fmaxf(v[c], 0.f);
            } else if (act == 2) {
                #pragma unroll
                for (int c = 0; c < 8; ++c)
                    v[c] = fmaxf(v[c], 0.f) + log1pf(expf(-fabsf(v[c])));
            }
            *(float4*)(Y + grow * 64 + col0)     = make_float4(v[0], v[1], v[2], v[3]);
            *(float4*)(Y + grow * 64 + col0 + 4) = make_float4(v[4], v[5], v[6], v[7]);
        }
    }
}

__global__ __launch_bounds__(256)
void pool_kernel(const float* __restrict__ a, const int* __restrict__ batch,
                 float* __restrict__ pooled, int n_atom)
{
    long idx = (long)blockIdx.x * 256 + threadIdx.x;
    int e = (int)(idx >> 6);
    if (e < n_atom) {
        int c = (int)(idx & 63);
        int g = batch[e];
        atomicAdd(pooled + (long)g * 64 + c, a[(long)e * 64 + c]);
    }
}

__global__ __launch_bounds__(256)
void pool_count_kernel(const int* __restrict__ batch, float* __restrict__ pcnt, int n_atom)
{
    int i = blockIdx.x * 256 + threadIdx.x;
    if (i < n_atom) atomicAdd(&pcnt[batch[i]], 1.0f);
}

__global__ __launch_bounds__(256)
void out_kernel(const float* __restrict__ h, const float* __restrict__ out_w,
                const float* __restrict__ out_b, float* __restrict__ out, int n)
{
    int g = blockIdx.x * 256 + threadIdx.x;
    if (g < n) {
        float s = 0.f;
        #pragma unroll
        for (int k = 0; k < 64; ++k) s = fmaf(h[(long)g * 64 + k], out_w[k], s);
        out[g] = s + out_b[0];
    }
}

extern "C" void kernel_launch(void* const* d_in, const int* in_sizes, int n_in,
                              void* d_out, int out_size, void* d_ws, size_t ws_size,
                              hipStream_t stream)
{
    const float* x_atom  = (const float*)d_in[0];
    const float* x_bond  = (const float*)d_in[1];
    const float* x_trip  = (const float*)d_in[2];
    const float* x_motif = (const float*)d_in[3];
    const int* ei[7];
    int ne[7];
    for (int r = 0; r < 7; ++r) {
        ei[r] = (const int*)d_in[4 + r];
        ne[r] = in_sizes[4 + r] / 2;
    }
    const int*   batch  = (const int*)d_in[11];
    const float* Wl     = (const float*)d_in[12];
    const float* bl     = (const float*)d_in[13];
    const float* Wr     = (const float*)d_in[14];
    const float* proj_w = (const float*)d_in[15];
    const float* proj_b = (const float*)d_in[16];
    const float* out_w  = (const float*)d_in[17];
    const float* out_b  = (const float*)d_in[18];

    const int NG = 1000;
    // type order: 0=m, 1=t, 2=b, 3=a
    const long tszN[4] = { 50000, 800000, 400000, 200000 };
    // relations: 0 mm, 1 mt, 2 tt, 3 tb, 4 bb, 5 ba, 6 aa
    const int rsrc[7] = { 0, 0, 1, 1, 2, 2, 3 };
    // per-dst-type relation lists (relB fused into Wr pass; -1 = none)
    // type t updates processed in order a(3), b(2), t(1), m(0)
    const int typeRel[4][2] = { {0,-1}, {1,2}, {3,4}, {5,6} };
    // count-buffer offsets per relation (by n_dst): mm,mt,tt,tb,bb,ba,aa
    const long coff[7] = { 0, 50000, 850000, 1650000, 2050000, 2450000, 2650000 };
    const long CTOT = 2850000;
    const long CHUNK = 200000;          // dst rows per agg chunk (51.2 MB)

    // ---- workspace layout ----
    char* p = (char*)d_ws;
    size_t used = 0;
    auto alloc = [&](size_t bytes) -> void* {
        void* r = (void*)p;
        size_t pad = (bytes + 255) & ~(size_t)255;
        p += pad; used += pad;
        return r;
    };
    float* slotA[4]; float* slotB[4];
    for (int t = 0; t < 4; ++t) slotA[t] = (float*)alloc(tszN[t] * 256);
    for (int t = 0; t < 4; ++t) slotB[t] = (float*)alloc(tszN[t] * 256);
    float* agg    = (float*)alloc((size_t)CHUNK * 256);
    int*   cntbuf = (int*)  alloc((size_t)CTOT * sizeof(int));
    float* pooled = (float*)alloc((size_t)NG * 256);
    float* pcnt   = (float*)alloc((size_t)NG * sizeof(float));
    float* hbuf   = (float*)alloc((size_t)NG * 256);

    if (used > ws_size) {
        // insufficient scratch: fail cleanly (absmax ~= max|ref|), don't OOB-write
        hipMemsetAsync(d_out, 0, (size_t)out_size * sizeof(float), stream);
        return;
    }

    // ---- edge counts (layer-invariant), stored as float counts ----
    hipMemsetAsync(cntbuf, 0, CTOT * sizeof(int), stream);
    for (int r = 0; r < 7; ++r)
        count_kernel<<<ceildiv_i(ne[r], 256), 256, 0, stream>>>(
            ei[r] + ne[r], ne[r], cntbuf + coff[r]);
    i2f_kernel<<<ceildiv_i(CTOT, 256), 256, 0, stream>>>(cntbuf, (int)CTOT);
    const float* cntf = (const float*)cntbuf;

    // ---- layers ----
    const float* cur[4] = { x_motif, x_trip, x_bond, x_atom };

    for (int l = 0; l < 3; ++l) {
        float** nxt = (l % 2 == 0) ? slotA : slotB;

        // update order a,b,t,m: each type's sources (self + upstream) still pre-layer
        const int order[4] = { 3, 2, 1, 0 };
        for (int oi = 0; oi < 4; ++oi) {
            int t = order[oi];
            long nD = tszN[t];
            int rA = typeRel[t][0], rB = typeRel[t][1];

            // 1) Wr pass: new = x_t @ (WrA (+WrB)).T + bA (+bB)
            gemm64_kernel<<<ceildiv_i(nD, 128), 256, 0, stream>>>(
                cur[t], (int)nD,
                Wr + (size_t)(l * 7 + rA) * 4096,
                (rB >= 0) ? Wr + (size_t)(l * 7 + rB) * 4096 : nullptr,
                nullptr,
                bl + (size_t)(l * 7 + rA) * 64,
                (rB >= 0) ? bl + (size_t)(l * 7 + rB) * 64 : nullptr,
                nullptr,
                nxt[t], 0);

            // 2) relation mean-aggregates, chunked over dst rows
            for (int ri = 0; ri < 2; ++ri) {
                int r = typeRel[t][ri];
                if (r < 0) continue;
                bool last = (ri == 1) || (typeRel[t][1] < 0);
                const float* xs = cur[rsrc[r]];
                for (long c0 = 0; c0 < nD; c0 += CHUNK) {
                    long cc = (nD - c0 < CHUNK) ? (nD - c0) : CHUNK;
                    hipMemsetAsync(agg, 0, (size_t)cc * 256, stream);
                    long nthreads = (long)ne[r] * 64;
                    scatter_chunk_kernel<<<ceildiv_i(nthreads, 256), 256, 0, stream>>>(
                        xs, ei[r], ei[r] + ne[r], (int)c0, (int)(c0 + cc),
                        agg, ne[r]);
                    gemm64_kernel<<<ceildiv_i(cc, 128), 256, 0, stream>>>(
                        agg, (int)cc,
                        Wl + (size_t)(l * 7 + r) * 4096, nullptr,
                        nxt[t] + c0 * 64,
                        nullptr, nullptr,
                        cntf + coff[r] + c0,
                        nxt[t] + c0 * 64, last ? 1 : 0);
                }
            }
        }
        for (int t = 0; t < 4; ++t) cur[t] = nxt[t];
    }

    // ---- pooling + MLP head ----
    hipMemsetAsync(pooled, 0, (size_t)NG * 256, stream);
    hipMemsetAsync(pcnt,   0, (size_t)NG * sizeof(float), stream);
    pool_kernel<<<ceildiv_i((long)tszN[3] * 64, 256), 256, 0, stream>>>(
        cur[3], batch, pooled, (int)tszN[3]);
    pool_count_kernel<<<ceildiv_i(tszN[3], 256), 256, 0, stream>>>(
        batch, pcnt, (int)tszN[3]);
    gemm64_kernel<<<ceildiv_i(NG, 128), 256, 0, stream>>>(
        pooled, NG, proj_w, nullptr, nullptr, proj_b, nullptr, pcnt, hbuf, 2);
    out_kernel<<<ceildiv_i(NG, 256), 256, 0, stream>>>(hbuf, out_w, out_b, (float*)d_out, NG);
}